// Round 5
// baseline (1087.962 us; speedup 1.0000x reference)
//
#include <hip/hip_runtime.h>
#include <hip/hip_bf16.h>

#define N_TOK 131072
#define NE 8
#define NOUT 10
#define NB 32
#define TAU 1e-4f

typedef float f32x4 __attribute__((ext_vector_type(4)));
typedef float f32x16 __attribute__((ext_vector_type(16)));
typedef __bf16 bf16x8 __attribute__((ext_vector_type(8)));
typedef unsigned short u16;
typedef unsigned short u16x8 __attribute__((ext_vector_type(8)));

// ws layout (bytes)
static constexpr size_t O_CNT  = 0;                               // cnt[8] @0, refCnt @32
static constexpr size_t O_LIST = 256;                             // 8*N*4
static constexpr size_t O_RCODE= O_LIST + 8ull*N_TOK*4;
static constexpr size_t O_RG   = O_RCODE + (size_t)N_TOK*4;
static constexpr size_t O_RL   = O_RG + (size_t)N_TOK*8;
static constexpr size_t O_W1   = O_RL + (size_t)N_TOK*4;          // 1MB  frag stream
static constexpr size_t O_W2   = O_W1 + 8ull*256*256*2;           // 512KB frag stream
static constexpr size_t O_W3   = O_W2 + 8ull*128*256*2;           // 64KB frag stream
static constexpr size_t O_W1G  = O_W3 + 8ull*32*128*2;            // 128KB gate W1 hi/lo
static constexpr size_t O_B0   = O_W1G + 131072;                  // N*10*4 = 5.24MB
static constexpr size_t O_B1   = O_B0 + (size_t)N_TOK*NOUT*4;
static constexpr size_t O_XBF  = O_B1 + (size_t)N_TOK*NOUT*4;     // N*256*2 = 64MB

static __device__ __forceinline__ u16 f2bf(float f) {
  union { float f; unsigned u; } v; v.f = f;
  unsigned r = v.u + 0x7FFFu + ((v.u >> 16) & 1u);
  return (u16)(r >> 16);
}
static __device__ __forceinline__ float bf2f(u16 h) {
  union { unsigned u; float f; } v; v.u = ((unsigned)h) << 16;
  return v.f;
}
static __device__ __forceinline__ float gelu_erf(float v) {
  return 0.5f * v * (1.0f + erff(v * 0.70710678118654752440f));
}
// Branchless A&S 7.1.26 erf-gelu: |erf err| <= 1.5e-7, ~12 VALU inst, no libcall.
static __device__ __forceinline__ float gelu_fast(float v) {
  float s = fabsf(v) * 0.70710678118654752440f;
  float t = __builtin_amdgcn_rcpf(fmaf(0.3275911f, s, 1.0f));
  float p = t * fmaf(t, fmaf(t, fmaf(t, fmaf(t, 1.061405429f, -1.453152027f),
                                     1.421413741f), -0.284496736f), 0.254829592f);
  float e = __builtin_amdgcn_exp2f(s * s * -1.44269504088896f);
  float erfa = fmaf(-p, e, 1.0f);
  return fmaf(0.5f * fabsf(v), erfa, 0.5f * v);
}

// ---- weight prep: fp32 -> bf16 per-MFMA fragment streams --------------------
__global__ __launch_bounds__(256) void prep_kernel(
    const float* __restrict__ eW1, const float* __restrict__ eW2,
    const float* __restrict__ eW3, const float* __restrict__ gW1,
    u16* __restrict__ w1f, u16* __restrict__ w2f, u16* __restrict__ w3f,
    u16* __restrict__ w1g)
{
  int id = blockIdx.x * 256 + threadIdx.x;
  u16x8 pk;
  if (id < 65536) {                       // expert W1: 8e x 8nt x 16ks x 64l
    int e = id >> 13, rem = id & 8191;
    int l = rem & 63;
    int n = ((rem >> 10) & 7)*32 + (l & 31);
    int k0 = (((rem >> 6) & 15)*2 + (l >> 5)) * 8;
#pragma unroll
    for (int j = 0; j < 8; ++j) pk[j] = f2bf(eW1[((size_t)(e*256 + k0 + j))*256 + n]);
    *(u16x8*)(w1f + (size_t)id*8) = pk;
  } else if (id < 98304) {                // expert W2: 8e x 4nt x 16ks x 64l
    int id2 = id - 65536;
    int e = id2 >> 12, rem = id2 & 4095;
    int l = rem & 63;
    int n = ((rem >> 10) & 3)*32 + (l & 31);
    int k0 = (((rem >> 6) & 15)*2 + (l >> 5)) * 8;
#pragma unroll
    for (int j = 0; j < 8; ++j) pk[j] = f2bf(eW2[((size_t)(e*256 + k0 + j))*128 + n]);
    *(u16x8*)(w2f + (size_t)id2*8) = pk;
  } else if (id < 102400) {               // expert W3 padded: 8e x 8ks x 64l
    int id3 = id - 98304;
    int e = id3 >> 9, ks = (id3 >> 6) & 7, l = id3 & 63;
    int n = l & 31;
    int k0 = (ks*2 + (l >> 5)) * 8;
#pragma unroll
    for (int j = 0; j < 8; ++j) {
      float v = (n < 10) ? eW3[((size_t)(e*128 + k0 + j))*10 + n] : 0.f;
      pk[j] = f2bf(v);
    }
    *(u16x8*)(w3f + (size_t)id3*8) = pk;
  } else {                                // gate W1 split hi/lo (LDS-staged path)
    int id4 = id - 102400;                // 8192 ids
    int gp = id4 & 7, r = (id4 >> 3) & 127, c = (id4 >> 10) & 3, pl = id4 >> 12;
    int k0 = c*64 + ((gp ^ (r & 7)) * 8);
#pragma unroll
    for (int j = 0; j < 8; ++j) {
      float v = gW1[(size_t)(k0 + j)*128 + r];
      u16 hi = f2bf(v);
      if (pl == 0) pk[j] = hi;
      else         pk[j] = f2bf(v - bf2f(hi));
    }
    *(u16x8*)(w1g + ((size_t)(pl*4 + c)*128 + r)*64 + gp*8) = pk;
  }
}

// ---- gate: split-bf16 MFMA GEMM + LN + gelu + logits + top2 (+ xbf export) --
__global__ __launch_bounds__(512) void gate_kernel(
    const float* __restrict__ x, const u16* __restrict__ w1g,
    const float* __restrict__ gb1, const float* __restrict__ glng,
    const float* __restrict__ glnb, const float* __restrict__ gW2,
    const float* __restrict__ gb2v, const float* __restrict__ temp,
    int* __restrict__ rcode, float2* __restrict__ rg,
    int* __restrict__ refCnt, int* __restrict__ refList,
    u16* __restrict__ xbf)
{
  extern __shared__ char gsm[];
  char* aHi = gsm;                        // [256 rows][8 gran][16B] 32KB
  char* aLo = gsm + 32768;
  char* wHi = gsm + 65536;                // [128 rows][8 gran][16B] 16KB
  char* wLo = gsm + 81920;
  char* gReg = gsm;                       // logits phase: [256][32 gran][16B] 128KB
  float* scr = (float*)(gsm + 131072);    // [256][20]

  const int tid = threadIdx.x;
  const int n0 = blockIdx.x * 256;
  const int w = tid >> 6, l = tid & 63;
  const int l31 = l & 31, lh = l >> 5;

  f32x16 acc[4];
#pragma unroll
  for (int nt = 0; nt < 4; ++nt) acc[nt] = (f32x16)0.f;

  const int rowA = w*32 + l31;
  const int swA = rowA & 7;

  for (int c = 0; c < 4; ++c) {
    __syncthreads();
#pragma unroll
    for (int it = 0; it < 4; ++it) {
      int G = tid + 512*it;
      int row = G >> 3, g = G & 7;
      const float* src = x + (size_t)(n0 + row)*256 + c*64 + g*8;
      f32x4 va = *(const f32x4*)src;
      f32x4 vb = *(const f32x4*)(src + 4);
      u16x8 hi, lo;
#pragma unroll
      for (int i = 0; i < 4; ++i) {
        u16 h = f2bf(va[i]); hi[i] = h; lo[i] = f2bf(va[i] - bf2f(h));
      }
#pragma unroll
      for (int i = 0; i < 4; ++i) {
        u16 h = f2bf(vb[i]); hi[4+i] = h; lo[4+i] = f2bf(vb[i] - bf2f(h));
      }
      int off = row*128 + ((g ^ (row & 7)) << 4);
      *(u16x8*)(aHi + off) = hi;
      *(u16x8*)(aLo + off) = lo;
      if (xbf) *(u16x8*)(xbf + (size_t)(n0 + row)*256 + c*64 + g*8) = hi;
    }
    {
      const u16* srcH = w1g + (size_t)c*8192;
      const u16* srcL = w1g + (size_t)(4 + c)*8192;
#pragma unroll
      for (int it = 0; it < 2; ++it) {
        int i = tid + 512*it;
        *(u16x8*)(wHi + i*16) = *(const u16x8*)(srcH + i*8);
        *(u16x8*)(wLo + i*16) = *(const u16x8*)(srcL + i*8);
      }
    }
    __syncthreads();
#pragma unroll
    for (int ks = 0; ks < 4; ++ks) {
      int gk = ks*2 + lh;
      bf16x8 afH = *(const bf16x8*)(aHi + rowA*128 + ((gk ^ swA) << 4));
      bf16x8 afL = *(const bf16x8*)(aLo + rowA*128 + ((gk ^ swA) << 4));
#pragma unroll
      for (int nt = 0; nt < 4; ++nt) {
        int rowB = nt*32 + l31;
        int off = rowB*128 + ((gk ^ (rowB & 7)) << 4);
        bf16x8 bfH = *(const bf16x8*)(wHi + off);
        bf16x8 bfL = *(const bf16x8*)(wLo + off);
        acc[nt] = __builtin_amdgcn_mfma_f32_32x32x16_bf16(afH, bfH, acc[nt], 0, 0, 0);
        acc[nt] = __builtin_amdgcn_mfma_f32_32x32x16_bf16(afL, bfH, acc[nt], 0, 0, 0);
        acc[nt] = __builtin_amdgcn_mfma_f32_32x32x16_bf16(afH, bfL, acc[nt], 0, 0, 0);
      }
    }
  }

  int colA[4]; float bia[4], ga[4], be[4];
#pragma unroll
  for (int nt = 0; nt < 4; ++nt) {
    colA[nt] = nt*32 + l31;
    bia[nt] = gb1[colA[nt]]; ga[nt] = glng[colA[nt]]; be[nt] = glnb[colA[nt]];
  }
#pragma unroll
  for (int nt = 0; nt < 4; ++nt)
#pragma unroll
    for (int j = 0; j < 16; ++j) acc[nt][j] += bia[nt];

  __syncthreads();

#pragma unroll
  for (int j = 0; j < 16; ++j) {
    float s = acc[0][j]+acc[1][j]+acc[2][j]+acc[3][j];
    float q = acc[0][j]*acc[0][j]+acc[1][j]*acc[1][j]+acc[2][j]*acc[2][j]+acc[3][j]*acc[3][j];
#pragma unroll
    for (int m = 1; m <= 16; m <<= 1) { s += __shfl_xor(s, m); q += __shfl_xor(q, m); }
    float mean = s * (1.f/128.f);
    float var = q * (1.f/128.f) - mean*mean;
    float rs = rsqrtf(var + 1e-5f);
    int r = w*32 + (j&3) + 8*(j>>2) + 4*lh;
    int rsw = r & 31;
#pragma unroll
    for (int nt = 0; nt < 4; ++nt) {
      float v = (acc[nt][j] - mean) * rs * ga[nt] + be[nt];
      v = gelu_erf(v);
      int col = colA[nt], gr = col >> 2;
      *(float*)(gReg + r*512 + ((gr ^ rsw) << 4) + (col & 3)*4) = v;
    }
  }
  __syncthreads();

  {
    int token = tid & 255, half = tid >> 8;
    int tsw = token & 31;
    float lacc[8];
#pragma unroll
    for (int e = 0; e < 8; ++e) lacc[e] = 0.f;
    for (int gr = 0; gr < 16; ++gr) {
      int grr = half*16 + gr;
      f32x4 g4 = *(const f32x4*)(gReg + token*512 + ((grr ^ tsw) << 4));
      const float* wb = gW2 + grr*32;
#pragma unroll
      for (int cc = 0; cc < 4; ++cc)
#pragma unroll
        for (int e = 0; e < 8; ++e) lacc[e] = fmaf(g4[cc], wb[cc*8 + e], lacc[e]);
    }
    f32x4 p0 = {lacc[0], lacc[1], lacc[2], lacc[3]};
    f32x4 p1 = {lacc[4], lacc[5], lacc[6], lacc[7]};
    *(f32x4*)(scr + token*20 + half*8)     = p0;
    *(f32x4*)(scr + token*20 + half*8 + 4) = p1;
  }
  __syncthreads();

  if (tid < 256) {
    float Tc = fminf(fmaxf(temp[0], 0.5f), 5.0f);
    float v[8];
#pragma unroll
    for (int e = 0; e < 8; ++e)
      v[e] = (scr[tid*20 + e] + scr[tid*20 + 8 + e] + gb2v[e]) / Tc;
    int i0 = 0; float b0 = v[0];
#pragma unroll
    for (int e = 1; e < 8; ++e) if (v[e] > b0) { b0 = v[e]; i0 = e; }
    int i1 = -1; float b1 = -3.4e38f;
#pragma unroll
    for (int e = 0; e < 8; ++e) if (e != i0 && v[e] > b1) { b1 = v[e]; i1 = e; }
    float v2 = -3.4e38f;
#pragma unroll
    for (int e = 0; e < 8; ++e) if (e != i0 && e != i1 && v[e] > v2) v2 = v[e];
    float a1 = expf(b1 - b0);
    float s = 1.0f + a1;
    float g0 = 1.0f / s, g1 = a1 / s;
    float tt = g0 + g1;
    g0 /= (tt + 1e-10f); g1 /= (tt + 1e-10f);
    int n = n0 + tid;
    rcode[n] = i0 | (i1 << 4);
    rg[n] = make_float2(g0, g1);
    if (b1 - v2 < TAU) {
      int p = atomicAdd(refCnt, 1);
      refList[p] = n;
    }
  }
}

// ---- refine: exact fp32 gate for near-tie tokens (1 wave/token) -------------
__global__ __launch_bounds__(256) void refine_kernel(
    const float* __restrict__ x, const float* __restrict__ gW1,
    const float* __restrict__ gb1, const float* __restrict__ glng,
    const float* __restrict__ glnb, const float* __restrict__ gW2,
    const float* __restrict__ gb2v, const float* __restrict__ temp,
    const int* __restrict__ refCnt, const int* __restrict__ refList,
    int* __restrict__ rcode, float2* __restrict__ rg)
{
  const int nref = refCnt[0];
  const int l = threadIdx.x & 63;
  const int wglob = (blockIdx.x * 256 + threadIdx.x) >> 6;
  const int wstep = (gridDim.x * 256) >> 6;

  for (int idx = wglob; idx < nref; idx += wstep) {
    int t = refList[idx];
    float a0 = gb1[l], a1 = gb1[l + 64];
    const float* xr = x + (size_t)t * 256;
    for (int k = 0; k < 256; ++k) {
      float xv = xr[k];
      a0 = fmaf(xv, gW1[(size_t)k*128 + l], a0);
      a1 = fmaf(xv, gW1[(size_t)k*128 + 64 + l], a1);
    }
    float s = a0 + a1, q = a0*a0 + a1*a1;
#pragma unroll
    for (int m = 1; m <= 32; m <<= 1) { s += __shfl_xor(s, m); q += __shfl_xor(q, m); }
    float mean = s * (1.f/128.f);
    float var = q * (1.f/128.f) - mean*mean;
    float rs = rsqrtf(var + 1e-5f);
    float g0v = gelu_erf((a0 - mean) * rs * glng[l] + glnb[l]);
    float g1v = gelu_erf((a1 - mean) * rs * glng[l + 64] + glnb[l + 64]);
    float lg[8];
#pragma unroll
    for (int e = 0; e < 8; ++e) {
      float p = g0v * gW2[l*8 + e] + g1v * gW2[(l + 64)*8 + e];
#pragma unroll
      for (int m = 1; m <= 32; m <<= 1) p += __shfl_xor(p, m);
      lg[e] = p;
    }
    if (l == 0) {
      float Tc = fminf(fmaxf(temp[0], 0.5f), 5.0f);
#pragma unroll
      for (int e = 0; e < 8; ++e) lg[e] = (lg[e] + gb2v[e]) / Tc;
      int i0 = 0; float b0 = lg[0];
#pragma unroll
      for (int e = 1; e < 8; ++e) if (lg[e] > b0) { b0 = lg[e]; i0 = e; }
      int i1 = -1; float b1 = -3.4e38f;
#pragma unroll
      for (int e = 0; e < 8; ++e) if (e != i0 && lg[e] > b1) { b1 = lg[e]; i1 = e; }
      float aa = expf(b1 - b0);
      float ss = 1.0f + aa;
      float g0 = 1.0f / ss, g1 = aa / ss;
      float tt = g0 + g1;
      g0 /= (tt + 1e-10f); g1 /= (tt + 1e-10f);
      rcode[t] = i0 | (i1 << 4);
      rg[t] = make_float2(g0, g1);
    }
  }
}

// ---- build per-expert token lists -------------------------------------------
__global__ __launch_bounds__(256) void lists_kernel(
    const int* __restrict__ rcode, int* __restrict__ cnt, int* __restrict__ list)
{
  __shared__ int lh[8], base[8];
  int tid = threadIdx.x;
  int n = blockIdx.x * 256 + tid;
  if (tid < 8) lh[tid] = 0;
  __syncthreads();
  int code = rcode[n];
  int i0 = code & 15, i1 = (code >> 4) & 15;
  int p0 = atomicAdd(&lh[i0], 1);
  int p1 = atomicAdd(&lh[i1], 1);
  __syncthreads();
  if (tid < 8) base[tid] = atomicAdd(cnt + tid, lh[tid]);
  __syncthreads();
  list[(size_t)i0*N_TOK + base[i0] + p0] = n;
  list[(size_t)i1*N_TOK + base[i1] + p1] = n | (int)0x80000000;
}

// ---- X row helpers (4 granule-quads = 64B bf16 per thread) ------------------
struct XR { u16x8 a, b, c, d; };
static __device__ __forceinline__ u16x8 pack8(f32x4 a, f32x4 b) {
  u16x8 p;
  p[0]=f2bf(a.x); p[1]=f2bf(a.y); p[2]=f2bf(a.z); p[3]=f2bf(a.w);
  p[4]=f2bf(b.x); p[5]=f2bf(b.y); p[6]=f2bf(b.z); p[7]=f2bf(b.w);
  return p;
}
static __device__ __forceinline__ XR load_xrow(const u16* xbf, const float* x,
                                               int tok, int l) {
  XR r;
  if (xbf) {
    const u16* s = xbf + (size_t)tok*256 + (l & 7)*32;
    r.a = *(const u16x8*)(s);      r.b = *(const u16x8*)(s + 8);
    r.c = *(const u16x8*)(s + 16); r.d = *(const u16x8*)(s + 24);
  } else {
    const float* s = x + (size_t)tok*256 + (l & 7)*32;
    r.a = pack8(*(const f32x4*)(s),      *(const f32x4*)(s + 4));
    r.b = pack8(*(const f32x4*)(s + 8),  *(const f32x4*)(s + 12));
    r.c = pack8(*(const f32x4*)(s + 16), *(const f32x4*)(s + 20));
    r.d = pack8(*(const f32x4*)(s + 24), *(const f32x4*)(s + 28));
  }
  return r;
}
static __device__ __forceinline__ void store_xrow(char* lds0, int row, int l, XR r) {
  int g0 = (l & 7)*4, sw = row & 7;
  char* base = lds0 + row*512;
  *(u16x8*)(base + (((g0+0) ^ sw) << 4)) = r.a;
  *(u16x8*)(base + (((g0+1) ^ sw) << 4)) = r.b;
  *(u16x8*)(base + (((g0+2) ^ sw) << 4)) = r.c;
  *(u16x8*)(base + (((g0+3) ^ sw) << 4)) = r.d;
}

// ---- experts: persistent blocks, weights in VGPRs, pipelined X gather -------
__global__ __launch_bounds__(512, 2) void expert_kernel(
    const float* __restrict__ x, const u16* __restrict__ xbf,
    const u16* __restrict__ w1f, const u16* __restrict__ w2f, const u16* __restrict__ w3f,
    const int* __restrict__ cnt, const int* __restrict__ list, const float2* __restrict__ rg,
    const float* __restrict__ eb1, const float* __restrict__ g1v, const float* __restrict__ b1v,
    const float* __restrict__ eb2, const float* __restrict__ g2v, const float* __restrict__ b2v,
    const float* __restrict__ eb3,
    float* __restrict__ ob0, float* __restrict__ ob1, float* __restrict__ outp)
{
  __shared__ char  lds0[64*512];          // X / H1: 64 rows x 512B (swizzled)
  __shared__ char  ldsH2[64*256];         // H2: 64 rows x 256B (swizzled)
  __shared__ float partS[64*8], partQ[64*8];
  __shared__ float meanv[64], rsv[64];
  __shared__ int   tokIl[2][64];
  __shared__ float tokWl[2][64];

  const int e = blockIdx.y;
  const int count = cnt[e];
  const int ntiles = (count + 63) >> 6;
  if ((int)blockIdx.x >= ntiles) return;

  const int tid = threadIdx.x;
  const int w = tid >> 6, l = tid & 63;
  const int l31 = l & 31, lh = l >> 5;
  const int sw = l31 & 7;

  // ---- load this expert's weight fragments into VGPRs (once) ----------------
  bf16x8 bw1[16], bw2[16], bw3[8];
  {
    const u16* p1 = w1f + (size_t)e*65536 + (size_t)w*8192 + l*8;
    const u16* p2 = w2f + (size_t)e*32768 + (size_t)(w >> 1)*8192 + l*8;
    const u16* p3 = w3f + (size_t)e*4096 + l*8;
#pragma unroll
    for (int ks = 0; ks < 16; ++ks) bw1[ks] = *(const bf16x8*)(p1 + ks*512);
#pragma unroll
    for (int ks = 0; ks < 16; ++ks) bw2[ks] = *(const bf16x8*)(p2 + ks*512);
#pragma unroll
    for (int ks = 0; ks < 8;  ++ks) bw3[ks] = *(const bf16x8*)(p3 + ks*512);
  }
  // per-column params
  const int col1 = w*32 + l31;
  const float eb1c = eb1[e*256 + col1], g1c = g1v[e*256 + col1], b1c = b1v[e*256 + col1];
  const int col2 = (w >> 1)*32 + l31;
  const float eb2c = eb2[e*128 + col2], g2c = g2v[e*128 + col2], b2c = b2v[e*128 + col2];
  const float b3c = (l31 < 10) ? eb3[e*10 + l31] : 0.f;

  const int rowX = w*8 + (l >> 3);

  // ---- prologue: meta + X for first tile ------------------------------------
  int tt = blockIdx.x;
  int cb = 0;
  {
    int raw0 = 0; float wgt0 = 0.f;
    if (l < 8) {
      int idx = tt*64 + w*8 + l;
      if (idx < count) {
        raw0 = list[(size_t)e*N_TOK + idx];
        float2 rr = rg[raw0 & 0x7fffffff];
        wgt0 = (raw0 < 0) ? rr.y : rr.x;
      }
    }
    int tok0 = __shfl(raw0, l >> 3) & 0x7fffffff;
    XR xr = load_xrow(xbf, x, tok0, l);
    store_xrow(lds0, rowX, l, xr);
    if (l < 8) { tokIl[0][w*8 + l] = raw0; tokWl[0][w*8 + l] = wgt0; }
    __syncthreads();
  }

  for (; tt < ntiles; tt += NB) {
    const int nvalid = min(64, count - tt*64);
    const int ttn = tt + NB;
    const bool hasNext = ttn < ntiles;

    // phase A: issue next-tile meta loads
    int rawN = 0; float wgtN = 0.f;
    if (hasNext && l < 8) {
      int idx = ttn*64 + w*8 + l;
      if (idx < count) {
        rawN = list[(size_t)e*N_TOK + idx];
        float2 rr = rg[rawN & 0x7fffffff];
        wgtN = (rawN < 0) ? rr.y : rr.x;
      }
    }

    // ---- L1: rows 0-63 x cols [w*32, w*32+32), B from VGPR ------------------
    f32x16 acc0 = (f32x16)0.f, acc1 = (f32x16)0.f;
#pragma unroll
    for (int ks = 0; ks < 16; ++ks) {
      int gk = ks*2 + lh;
      bf16x8 a0 = *(const bf16x8*)(lds0 + l31*512 + ((gk ^ sw) << 4));
      bf16x8 a1 = *(const bf16x8*)(lds0 + (32 + l31)*512 + ((gk ^ sw) << 4));
      acc0 = __builtin_amdgcn_mfma_f32_32x32x16_bf16(a0, bw1[ks], acc0, 0, 0, 0);
      acc1 = __builtin_amdgcn_mfma_f32_32x32x16_bf16(a1, bw1[ks], acc1, 0, 0, 0);
    }
#pragma unroll
    for (int j = 0; j < 16; ++j) { acc0[j] += eb1c; acc1[j] += eb1c; }

    // phase B: issue next-tile X loads (latency hidden under LN1/L2)
    XR xrN;
    int tokN = __shfl(rawN, l >> 3) & 0x7fffffff;
    if (hasNext) xrN = load_xrow(xbf, x, tokN, l);

    // LN1 partials (per wave: 32 cols of rows 0-63)
#pragma unroll
    for (int j = 0; j < 16; ++j) {
      float s0 = acc0[j], q0 = s0*s0;
      float s1 = acc1[j], q1 = s1*s1;
#pragma unroll
      for (int m = 1; m <= 16; m <<= 1) {
        s0 += __shfl_xor(s0, m); q0 += __shfl_xor(q0, m);
        s1 += __shfl_xor(s1, m); q1 += __shfl_xor(q1, m);
      }
      if (l31 == 0) {
        int r = (j&3) + 8*(j>>2) + 4*lh;
        partS[r*8 + w] = s0;        partQ[r*8 + w] = q0;
        partS[(32 + r)*8 + w] = s1; partQ[(32 + r)*8 + w] = q1;
      }
    }
    __syncthreads();                      // B1
    {
      int r = rowX, k = l & 7;
      float s = partS[r*8 + k], q = partQ[r*8 + k];
#pragma unroll
      for (int m = 1; m <= 4; m <<= 1) { s += __shfl_xor(s, m); q += __shfl_xor(q, m); }
      if (k == 0) {
        float mn = s * (1.f/256.f);
        float vr = q * (1.f/256.f) - mn*mn;
        meanv[r] = mn; rsv[r] = rsqrtf(vr + 1e-5f);
      }
    }
    __syncthreads();                      // B2
    // H1 = gelu(LN1) -> lds0 (overwrites X)
#pragma unroll
    for (int j = 0; j < 16; ++j) {
      int r = (j&3) + 8*(j>>2) + 4*lh;
      float v0 = gelu_fast((acc0[j] - meanv[r]) * rsv[r] * g1c + b1c);
      float v1 = gelu_fast((acc1[j] - meanv[32 + r]) * rsv[32 + r] * g1c + b1c);
      float o0 = __shfl_xor(v0, 1), o1 = __shfl_xor(v1, 1);
      if ((l & 1) == 0) {
        unsigned pk0 = (unsigned)f2bf(v0) | ((unsigned)f2bf(o0) << 16);
        unsigned pk1 = (unsigned)f2bf(v1) | ((unsigned)f2bf(o1) << 16);
        int cbyte = col1*2;
        *(unsigned*)(lds0 + r*512 + (cbyte ^ ((r & 7) << 4))) = pk0;
        *(unsigned*)(lds0 + (32 + r)*512 + (cbyte ^ ((r & 7) << 4))) = pk1;
      }
    }
    __syncthreads();                      // B3
    // ---- L2: rows (w&1)*32.. x cols [col2 tile), B from VGPR ----------------
    f32x16 accB = (f32x16)0.f;
    {
      int rA2 = (w & 1)*32 + l31;
#pragma unroll
      for (int ks = 0; ks < 16; ++ks) {
        int gk = ks*2 + lh;
        bf16x8 a = *(const bf16x8*)(lds0 + rA2*512 + ((gk ^ sw) << 4));
        accB = __builtin_amdgcn_mfma_f32_32x32x16_bf16(a, bw2[ks], accB, 0, 0, 0);
      }
    }
#pragma unroll
    for (int j = 0; j < 16; ++j) accB[j] += eb2c;
    // LN2 partials (4 partials/row, index w>>1)
#pragma unroll
    for (int j = 0; j < 16; ++j) {
      float s = accB[j], q = s*s;
#pragma unroll
      for (int m = 1; m <= 16; m <<= 1) { s += __shfl_xor(s, m); q += __shfl_xor(q, m); }
      if (l31 == 0) {
        int r = (w & 1)*32 + (j&3) + 8*(j>>2) + 4*lh;
        partS[r*4 + (w >> 1)] = s; partQ[r*4 + (w >> 1)] = q;
      }
    }
    __syncthreads();                      // B4
    {
      int r = rowX, k = l & 7;
      float s = (k < 4) ? partS[r*4 + k] : 0.f;
      float q = (k < 4) ? partQ[r*4 + k] : 0.f;
#pragma unroll
      for (int m = 1; m <= 4; m <<= 1) { s += __shfl_xor(s, m); q += __shfl_xor(q, m); }
      if (k == 0) {
        float mn = s * (1.f/128.f);
        float vr = q * (1.f/128.f) - mn*mn;
        meanv[r] = mn; rsv[r] = rsqrtf(vr + 1e-5f);
      }
    }
    __syncthreads();                      // B5
    // H2 = gelu(LN2) -> ldsH2
#pragma unroll
    for (int j = 0; j < 16; ++j) {
      int r = (w & 1)*32 + (j&3) + 8*(j>>2) + 4*lh;
      float v = gelu_fast((accB[j] - meanv[r]) * rsv[r] * g2c + b2c);
      float o = __shfl_xor(v, 1);
      if ((l & 1) == 0) {
        unsigned pk = (unsigned)f2bf(v) | ((unsigned)f2bf(o) << 16);
        int cbyte = col2*2;
        *(unsigned*)(ldsH2 + r*256 + (cbyte ^ ((r & 7) << 4))) = pk;
      }
    }
    __syncthreads();                      // B6
    // phase E: stage next X into lds0 (all waves) + L3 (waves 0-1)
    if (hasNext) {
      store_xrow(lds0, rowX, l, xrN);
      if (l < 8) { tokIl[cb ^ 1][w*8 + l] = rawN; tokWl[cb ^ 1][w*8 + l] = wgtN; }
    }
    if (w < 2) {
      f32x16 accC = (f32x16)0.f;
      int rC = w*32 + l31;
#pragma unroll
      for (int ks = 0; ks < 8; ++ks) {
        int gk = ks*2 + lh;
        bf16x8 a = *(const bf16x8*)(ldsH2 + rC*256 + ((gk ^ sw) << 4));
        accC = __builtin_amdgcn_mfma_f32_32x32x16_bf16(a, bw3[ks], accC, 0, 0, 0);
      }
#pragma unroll
      for (int j = 0; j < 16; ++j) {
        int rl = w*32 + (j&3) + 8*(j>>2) + 4*lh;
        if (rl < nvalid && l31 < 10) {
          int raw = tokIl[cb][rl];
          int tok = raw & 0x7fffffff;
          float val = (accC[j] + b3c) * tokWl[cb][rl];
          if (ob0) {
            float* dst = (raw < 0) ? ob1 : ob0;
            dst[(size_t)tok*10 + l31] = val;
          } else {
            atomicAdd(outp + (size_t)tok*10 + l31, val);
          }
        }
      }
    }
    __syncthreads();                      // B7 (loop end)
    cb ^= 1;
  }
}

__global__ __launch_bounds__(256) void combine_kernel(
    const float* __restrict__ b0, const float* __restrict__ b1,
    float* __restrict__ y, int n)
{
  int i = blockIdx.x * 256 + threadIdx.x;
  if (i < n) y[i] = b0[i] + b1[i];
}

extern "C" void kernel_launch(void* const* d_in, const int* in_sizes, int n_in,
                              void* d_out, int out_size, void* d_ws, size_t ws_size,
                              hipStream_t stream) {
  const float* x     = (const float*)d_in[0];
  const float* gW1   = (const float*)d_in[1];
  const float* gb1   = (const float*)d_in[2];
  const float* glng  = (const float*)d_in[3];
  const float* glnb  = (const float*)d_in[4];
  const float* gW2   = (const float*)d_in[5];
  const float* gb2   = (const float*)d_in[6];
  const float* temp  = (const float*)d_in[7];
  const float* eW1   = (const float*)d_in[8];
  const float* eb1   = (const float*)d_in[9];
  const float* elng1 = (const float*)d_in[10];
  const float* elnb1 = (const float*)d_in[11];
  const float* eW2   = (const float*)d_in[12];
  const float* eb2   = (const float*)d_in[13];
  const float* elng2 = (const float*)d_in[14];
  const float* elnb2 = (const float*)d_in[15];
  const float* eW3   = (const float*)d_in[16];
  const float* eb3   = (const float*)d_in[17];

  char* ws = (char*)d_ws;
  int*    cnt     = (int*)(ws + O_CNT);
  int*    refCnt  = (int*)(ws + O_CNT + 32);
  int*    list    = (int*)(ws + O_LIST);
  int*    rcode   = (int*)(ws + O_RCODE);
  float2* rgp     = (float2*)(ws + O_RG);
  int*    refList = (int*)(ws + O_RL);
  u16*    w1f     = (u16*)(ws + O_W1);
  u16*    w2f     = (u16*)(ws + O_W2);
  u16*    w3f     = (u16*)(ws + O_W3);
  u16*    w1g     = (u16*)(ws + O_W1G);
  bool useBuf     = ws_size >= O_XBF;
  float*  b0      = useBuf ? (float*)(ws + O_B0) : nullptr;
  float*  b1      = useBuf ? (float*)(ws + O_B1) : nullptr;
  u16*    xbf     = (ws_size >= O_XBF + (size_t)N_TOK*512)
                    ? (u16*)(ws + O_XBF) : nullptr;

  hipMemsetAsync(cnt, 0, 256, stream);
  hipMemsetAsync(d_out, 0, (size_t)out_size * 4, stream);

  prep_kernel<<<432, 256, 0, stream>>>(eW1, eW2, eW3, gW1, w1f, w2f, w3f, w1g);

  int gate_smem = 151552;
  hipFuncSetAttribute((const void*)gate_kernel,
                      hipFuncAttributeMaxDynamicSharedMemorySize, gate_smem);
  gate_kernel<<<512, 512, gate_smem, stream>>>(x, w1g, gb1, glng, glnb, gW2, gb2,
                                               temp, rcode, rgp, refCnt, refList, xbf);

  refine_kernel<<<128, 256, 0, stream>>>(x, gW1, gb1, glng, glnb, gW2, gb2, temp,
                                         refCnt, refList, rcode, rgp);

  lists_kernel<<<512, 256, 0, stream>>>(rcode, cnt, list);

  expert_kernel<<<dim3(NB, NE), 512, 0, stream>>>(
      x, xbf, w1f, w2f, w3f, cnt, list, rgp,
      eb1, elng1, elnb1, eb2, elng2, elnb2, eb3, b0, b1, (float*)d_out);

  if (useBuf)
    combine_kernel<<<(N_TOK*NOUT + 255)/256, 256, 0, stream>>>(
        b0, b1, (float*)d_out, N_TOK*NOUT);
}

// Round 6
// 465.447 us; speedup vs baseline: 2.3375x; 2.3375x over previous
//
#include <hip/hip_runtime.h>
#include <hip/hip_bf16.h>

#define N_TOK 131072
#define NE 8
#define NOUT 10
#define BM 64
#define TAU 1e-4f

typedef float f32x4 __attribute__((ext_vector_type(4)));
typedef float f32x16 __attribute__((ext_vector_type(16)));
typedef __bf16 bf16x8 __attribute__((ext_vector_type(8)));
typedef unsigned short u16;
typedef unsigned short u16x8 __attribute__((ext_vector_type(8)));

// ws layout (bytes)
static constexpr size_t O_CNT  = 0;                               // cnt[8] @0, refCnt @32
static constexpr size_t O_LIST = 256;                             // 8*N*4
static constexpr size_t O_RCODE= O_LIST + 8ull*N_TOK*4;
static constexpr size_t O_RG   = O_RCODE + (size_t)N_TOK*4;
static constexpr size_t O_RL   = O_RG + (size_t)N_TOK*8;
static constexpr size_t O_W1   = O_RL + (size_t)N_TOK*4;          // 1MB  frag stream
static constexpr size_t O_W2   = O_W1 + 8ull*256*256*2;           // 512KB frag stream
static constexpr size_t O_W3   = O_W2 + 8ull*128*256*2;           // 64KB frag stream
static constexpr size_t O_W1G  = O_W3 + 8ull*32*128*2;            // 128KB gate W1 hi/lo
static constexpr size_t O_B0   = O_W1G + 131072;                  // N*10*4 = 5.24MB
static constexpr size_t O_B1   = O_B0 + (size_t)N_TOK*NOUT*4;
static constexpr size_t O_XBF  = O_B1 + (size_t)N_TOK*NOUT*4;     // N*256*2 = 64MB

static __device__ __forceinline__ u16 f2bf(float f) {
  union { float f; unsigned u; } v; v.f = f;
  unsigned r = v.u + 0x7FFFu + ((v.u >> 16) & 1u);
  return (u16)(r >> 16);
}
static __device__ __forceinline__ float bf2f(u16 h) {
  union { unsigned u; float f; } v; v.u = ((unsigned)h) << 16;
  return v.f;
}
static __device__ __forceinline__ float gelu_erf(float v) {
  return 0.5f * v * (1.0f + erff(v * 0.70710678118654752440f));
}
// Branchless A&S 7.1.26 erf-gelu: |erf err| <= 1.5e-7, ~12 VALU inst, no libcall.
static __device__ __forceinline__ float gelu_fast(float v) {
  float s = fabsf(v) * 0.70710678118654752440f;
  float t = __builtin_amdgcn_rcpf(fmaf(0.3275911f, s, 1.0f));
  float p = t * fmaf(t, fmaf(t, fmaf(t, fmaf(t, 1.061405429f, -1.453152027f),
                                     1.421413741f), -0.284496736f), 0.254829592f);
  float e = __builtin_amdgcn_exp2f(s * s * -1.44269504088896f);
  float erfa = fmaf(-p, e, 1.0f);
  return fmaf(0.5f * fabsf(v), erfa, 0.5f * v);
}

// ---- weight prep: fp32 -> bf16 per-MFMA fragment streams --------------------
// Fragment layout: [ntile][ks][lane(64)][8 u16]; lane l holds B row
// n = ntile*32 + (l&31), k elements (ks*2 + (l>>5))*8 .. +7.
__global__ __launch_bounds__(256) void prep_kernel(
    const float* __restrict__ eW1, const float* __restrict__ eW2,
    const float* __restrict__ eW3, const float* __restrict__ gW1,
    u16* __restrict__ w1f, u16* __restrict__ w2f, u16* __restrict__ w3f,
    u16* __restrict__ w1g)
{
  int id = blockIdx.x * 256 + threadIdx.x;
  u16x8 pk;
  if (id < 65536) {                       // expert W1: 8e x 8nt x 16ks x 64l
    int e = id >> 13, rem = id & 8191;
    int l = rem & 63;
    int n = ((rem >> 10) & 7)*32 + (l & 31);
    int k0 = (((rem >> 6) & 15)*2 + (l >> 5)) * 8;
#pragma unroll
    for (int j = 0; j < 8; ++j) pk[j] = f2bf(eW1[((size_t)(e*256 + k0 + j))*256 + n]);
    *(u16x8*)(w1f + (size_t)id*8) = pk;
  } else if (id < 98304) {                // expert W2: 8e x 4nt x 16ks x 64l
    int id2 = id - 65536;
    int e = id2 >> 12, rem = id2 & 4095;
    int l = rem & 63;
    int n = ((rem >> 10) & 3)*32 + (l & 31);
    int k0 = (((rem >> 6) & 15)*2 + (l >> 5)) * 8;
#pragma unroll
    for (int j = 0; j < 8; ++j) pk[j] = f2bf(eW2[((size_t)(e*256 + k0 + j))*128 + n]);
    *(u16x8*)(w2f + (size_t)id2*8) = pk;
  } else if (id < 102400) {               // expert W3 padded: 8e x 8ks x 64l
    int id3 = id - 98304;
    int e = id3 >> 9, ks = (id3 >> 6) & 7, l = id3 & 63;
    int n = l & 31;
    int k0 = (ks*2 + (l >> 5)) * 8;
#pragma unroll
    for (int j = 0; j < 8; ++j) {
      float v = (n < 10) ? eW3[((size_t)(e*128 + k0 + j))*10 + n] : 0.f;
      pk[j] = f2bf(v);
    }
    *(u16x8*)(w3f + (size_t)id3*8) = pk;
  } else {                                // gate W1 split hi/lo (LDS-staged path)
    int id4 = id - 102400;                // 8192 ids
    int gp = id4 & 7, r = (id4 >> 3) & 127, c = (id4 >> 10) & 3, pl = id4 >> 12;
    int k0 = c*64 + ((gp ^ (r & 7)) * 8);
#pragma unroll
    for (int j = 0; j < 8; ++j) {
      float v = gW1[(size_t)(k0 + j)*128 + r];
      u16 hi = f2bf(v);
      if (pl == 0) pk[j] = hi;
      else         pk[j] = f2bf(v - bf2f(hi));
    }
    *(u16x8*)(w1g + ((size_t)(pl*4 + c)*128 + r)*64 + gp*8) = pk;
  }
}

// ---- gate: split-bf16 MFMA GEMM + LN + gelu + logits + top2 (+ xbf export) --
__global__ __launch_bounds__(512) void gate_kernel(
    const float* __restrict__ x, const u16* __restrict__ w1g,
    const float* __restrict__ gb1, const float* __restrict__ glng,
    const float* __restrict__ glnb, const float* __restrict__ gW2,
    const float* __restrict__ gb2v, const float* __restrict__ temp,
    int* __restrict__ rcode, float2* __restrict__ rg,
    int* __restrict__ refCnt, int* __restrict__ refList,
    u16* __restrict__ xbf)
{
  extern __shared__ char gsm[];
  char* aHi = gsm;                        // [256 rows][8 gran][16B] 32KB
  char* aLo = gsm + 32768;
  char* wHi = gsm + 65536;                // [128 rows][8 gran][16B] 16KB
  char* wLo = gsm + 81920;
  char* gReg = gsm;                       // logits phase: [256][32 gran][16B] 128KB
  float* scr = (float*)(gsm + 131072);    // [256][20]

  const int tid = threadIdx.x;
  const int n0 = blockIdx.x * 256;
  const int w = tid >> 6, l = tid & 63;
  const int l31 = l & 31, lh = l >> 5;

  f32x16 acc[4];
#pragma unroll
  for (int nt = 0; nt < 4; ++nt) acc[nt] = (f32x16)0.f;

  const int rowA = w*32 + l31;
  const int swA = rowA & 7;

  for (int c = 0; c < 4; ++c) {
    __syncthreads();
#pragma unroll
    for (int it = 0; it < 4; ++it) {
      int G = tid + 512*it;
      int row = G >> 3, g = G & 7;
      const float* src = x + (size_t)(n0 + row)*256 + c*64 + g*8;
      f32x4 va = *(const f32x4*)src;
      f32x4 vb = *(const f32x4*)(src + 4);
      u16x8 hi, lo;
#pragma unroll
      for (int i = 0; i < 4; ++i) {
        u16 h = f2bf(va[i]); hi[i] = h; lo[i] = f2bf(va[i] - bf2f(h));
      }
#pragma unroll
      for (int i = 0; i < 4; ++i) {
        u16 h = f2bf(vb[i]); hi[4+i] = h; lo[4+i] = f2bf(vb[i] - bf2f(h));
      }
      int off = row*128 + ((g ^ (row & 7)) << 4);
      *(u16x8*)(aHi + off) = hi;
      *(u16x8*)(aLo + off) = lo;
      if (xbf) *(u16x8*)(xbf + (size_t)(n0 + row)*256 + c*64 + g*8) = hi;
    }
    {
      const u16* srcH = w1g + (size_t)c*8192;
      const u16* srcL = w1g + (size_t)(4 + c)*8192;
#pragma unroll
      for (int it = 0; it < 2; ++it) {
        int i = tid + 512*it;
        *(u16x8*)(wHi + i*16) = *(const u16x8*)(srcH + i*8);
        *(u16x8*)(wLo + i*16) = *(const u16x8*)(srcL + i*8);
      }
    }
    __syncthreads();
#pragma unroll
    for (int ks = 0; ks < 4; ++ks) {
      int gk = ks*2 + lh;
      bf16x8 afH = *(const bf16x8*)(aHi + rowA*128 + ((gk ^ swA) << 4));
      bf16x8 afL = *(const bf16x8*)(aLo + rowA*128 + ((gk ^ swA) << 4));
#pragma unroll
      for (int nt = 0; nt < 4; ++nt) {
        int rowB = nt*32 + l31;
        int off = rowB*128 + ((gk ^ (rowB & 7)) << 4);
        bf16x8 bfH = *(const bf16x8*)(wHi + off);
        bf16x8 bfL = *(const bf16x8*)(wLo + off);
        acc[nt] = __builtin_amdgcn_mfma_f32_32x32x16_bf16(afH, bfH, acc[nt], 0, 0, 0);
        acc[nt] = __builtin_amdgcn_mfma_f32_32x32x16_bf16(afL, bfH, acc[nt], 0, 0, 0);
        acc[nt] = __builtin_amdgcn_mfma_f32_32x32x16_bf16(afH, bfL, acc[nt], 0, 0, 0);
      }
    }
  }

  int colA[4]; float bia[4], ga[4], be[4];
#pragma unroll
  for (int nt = 0; nt < 4; ++nt) {
    colA[nt] = nt*32 + l31;
    bia[nt] = gb1[colA[nt]]; ga[nt] = glng[colA[nt]]; be[nt] = glnb[colA[nt]];
  }
#pragma unroll
  for (int nt = 0; nt < 4; ++nt)
#pragma unroll
    for (int j = 0; j < 16; ++j) acc[nt][j] += bia[nt];

  __syncthreads();

#pragma unroll
  for (int j = 0; j < 16; ++j) {
    float s = acc[0][j]+acc[1][j]+acc[2][j]+acc[3][j];
    float q = acc[0][j]*acc[0][j]+acc[1][j]*acc[1][j]+acc[2][j]*acc[2][j]+acc[3][j]*acc[3][j];
#pragma unroll
    for (int m = 1; m <= 16; m <<= 1) { s += __shfl_xor(s, m); q += __shfl_xor(q, m); }
    float mean = s * (1.f/128.f);
    float var = q * (1.f/128.f) - mean*mean;
    float rs = rsqrtf(var + 1e-5f);
    int r = w*32 + (j&3) + 8*(j>>2) + 4*lh;
    int rsw = r & 31;
#pragma unroll
    for (int nt = 0; nt < 4; ++nt) {
      float v = (acc[nt][j] - mean) * rs * ga[nt] + be[nt];
      v = gelu_erf(v);
      int col = colA[nt], gr = col >> 2;
      *(float*)(gReg + r*512 + ((gr ^ rsw) << 4) + (col & 3)*4) = v;
    }
  }
  __syncthreads();

  {
    int token = tid & 255, half = tid >> 8;
    int tsw = token & 31;
    float lacc[8];
#pragma unroll
    for (int e = 0; e < 8; ++e) lacc[e] = 0.f;
    for (int gr = 0; gr < 16; ++gr) {
      int grr = half*16 + gr;
      f32x4 g4 = *(const f32x4*)(gReg + token*512 + ((grr ^ tsw) << 4));
      const float* wb = gW2 + grr*32;
#pragma unroll
      for (int cc = 0; cc < 4; ++cc)
#pragma unroll
        for (int e = 0; e < 8; ++e) lacc[e] = fmaf(g4[cc], wb[cc*8 + e], lacc[e]);
    }
    f32x4 p0 = {lacc[0], lacc[1], lacc[2], lacc[3]};
    f32x4 p1 = {lacc[4], lacc[5], lacc[6], lacc[7]};
    *(f32x4*)(scr + token*20 + half*8)     = p0;
    *(f32x4*)(scr + token*20 + half*8 + 4) = p1;
  }
  __syncthreads();

  if (tid < 256) {
    float Tc = fminf(fmaxf(temp[0], 0.5f), 5.0f);
    float v[8];
#pragma unroll
    for (int e = 0; e < 8; ++e)
      v[e] = (scr[tid*20 + e] + scr[tid*20 + 8 + e] + gb2v[e]) / Tc;
    int i0 = 0; float b0 = v[0];
#pragma unroll
    for (int e = 1; e < 8; ++e) if (v[e] > b0) { b0 = v[e]; i0 = e; }
    int i1 = -1; float b1 = -3.4e38f;
#pragma unroll
    for (int e = 0; e < 8; ++e) if (e != i0 && v[e] > b1) { b1 = v[e]; i1 = e; }
    float v2 = -3.4e38f;
#pragma unroll
    for (int e = 0; e < 8; ++e) if (e != i0 && e != i1 && v[e] > v2) v2 = v[e];
    float a1 = expf(b1 - b0);
    float s = 1.0f + a1;
    float g0 = 1.0f / s, g1 = a1 / s;
    float tt = g0 + g1;
    g0 /= (tt + 1e-10f); g1 /= (tt + 1e-10f);
    int n = n0 + tid;
    rcode[n] = i0 | (i1 << 4);
    rg[n] = make_float2(g0, g1);
    if (b1 - v2 < TAU) {
      int p = atomicAdd(refCnt, 1);
      refList[p] = n;
    }
  }
}

// ---- refine: exact fp32 gate for near-tie tokens (1 wave/token) -------------
__global__ __launch_bounds__(256) void refine_kernel(
    const float* __restrict__ x, const float* __restrict__ gW1,
    const float* __restrict__ gb1, const float* __restrict__ glng,
    const float* __restrict__ glnb, const float* __restrict__ gW2,
    const float* __restrict__ gb2v, const float* __restrict__ temp,
    const int* __restrict__ refCnt, const int* __restrict__ refList,
    int* __restrict__ rcode, float2* __restrict__ rg)
{
  const int nref = refCnt[0];
  const int l = threadIdx.x & 63;
  const int wglob = (blockIdx.x * 256 + threadIdx.x) >> 6;
  const int wstep = (gridDim.x * 256) >> 6;

  for (int idx = wglob; idx < nref; idx += wstep) {
    int t = refList[idx];
    float a0 = gb1[l], a1 = gb1[l + 64];
    const float* xr = x + (size_t)t * 256;
    for (int k = 0; k < 256; ++k) {
      float xv = xr[k];
      a0 = fmaf(xv, gW1[(size_t)k*128 + l], a0);
      a1 = fmaf(xv, gW1[(size_t)k*128 + 64 + l], a1);
    }
    float s = a0 + a1, q = a0*a0 + a1*a1;
#pragma unroll
    for (int m = 1; m <= 32; m <<= 1) { s += __shfl_xor(s, m); q += __shfl_xor(q, m); }
    float mean = s * (1.f/128.f);
    float var = q * (1.f/128.f) - mean*mean;
    float rs = rsqrtf(var + 1e-5f);
    float g0v = gelu_erf((a0 - mean) * rs * glng[l] + glnb[l]);
    float g1v = gelu_erf((a1 - mean) * rs * glng[l + 64] + glnb[l + 64]);
    float lg[8];
#pragma unroll
    for (int e = 0; e < 8; ++e) {
      float p = g0v * gW2[l*8 + e] + g1v * gW2[(l + 64)*8 + e];
#pragma unroll
      for (int m = 1; m <= 32; m <<= 1) p += __shfl_xor(p, m);
      lg[e] = p;
    }
    if (l == 0) {
      float Tc = fminf(fmaxf(temp[0], 0.5f), 5.0f);
#pragma unroll
      for (int e = 0; e < 8; ++e) lg[e] = (lg[e] + gb2v[e]) / Tc;
      int i0 = 0; float b0 = lg[0];
#pragma unroll
      for (int e = 1; e < 8; ++e) if (lg[e] > b0) { b0 = lg[e]; i0 = e; }
      int i1 = -1; float b1 = -3.4e38f;
#pragma unroll
      for (int e = 0; e < 8; ++e) if (e != i0 && lg[e] > b1) { b1 = lg[e]; i1 = e; }
      float aa = expf(b1 - b0);
      float ss = 1.0f + aa;
      float g0 = 1.0f / ss, g1 = aa / ss;
      float tt = g0 + g1;
      g0 /= (tt + 1e-10f); g1 /= (tt + 1e-10f);
      rcode[t] = i0 | (i1 << 4);
      rg[t] = make_float2(g0, g1);
    }
  }
}

// ---- build per-expert token lists -------------------------------------------
__global__ __launch_bounds__(256) void lists_kernel(
    const int* __restrict__ rcode, int* __restrict__ cnt, int* __restrict__ list)
{
  __shared__ int lh[8], base[8];
  int tid = threadIdx.x;
  int n = blockIdx.x * 256 + tid;
  if (tid < 8) lh[tid] = 0;
  __syncthreads();
  int code = rcode[n];
  int i0 = code & 15, i1 = (code >> 4) & 15;
  int p0 = atomicAdd(&lh[i0], 1);
  int p1 = atomicAdd(&lh[i1], 1);
  __syncthreads();
  if (tid < 8) base[tid] = atomicAdd(cnt + tid, lh[tid]);
  __syncthreads();
  list[(size_t)i0*N_TOK + base[i0] + p0] = n;
  list[(size_t)i1*N_TOK + base[i1] + p1] = n | (int)0x80000000;
}

// ---- experts: BM=64 tiles, fused 3-layer MLP, B streamed from L2, stores ----
__global__ __launch_bounds__(512, 6) void expert_kernel(
    const float* __restrict__ x, const u16* __restrict__ xbf,
    const u16* __restrict__ w1f, const u16* __restrict__ w2f, const u16* __restrict__ w3f,
    const int* __restrict__ cnt, const int* __restrict__ list, const float2* __restrict__ rg,
    const float* __restrict__ eb1, const float* __restrict__ g1v, const float* __restrict__ b1v,
    const float* __restrict__ eb2, const float* __restrict__ g2v, const float* __restrict__ b2v,
    const float* __restrict__ eb3,
    float* __restrict__ ob0, float* __restrict__ ob1, float* __restrict__ outp)
{
  extern __shared__ char smem[];
  char*  lds0  = smem;                    // 32KB: X/H1 [64][32][16B]; H2 [64][16][16B]
  float* partS = (float*)(smem + 32768);  // [64][4]
  float* partQ = partS + 256;
  float* meanv = partQ + 256;             // [64]
  float* rsv   = meanv + 64;
  int*   tokI  = (int*)(rsv + 64);        // [64]
  float* tokW  = (float*)(tokI + 64);     // [64]

  const int e = blockIdx.y;
  const int count = cnt[e];
  const int base = blockIdx.x * BM;
  if (base >= count) return;
  const int nvalid = min(BM, count - base);

  const int tid = threadIdx.x;
  const int w = tid >> 6, l = tid & 63;
  const int l31 = l & 31, lh = l >> 5;
  const int wm = w & 1, wn = w >> 1;      // wm: row-tile(2x32), wn: col-group(4)

  if (tid < BM) {
    int raw = 0; float wgt = 0.f;
    if (tid < nvalid) {
      raw = list[(size_t)e*N_TOK + base + tid];
      float2 rr = rg[raw & 0x7fffffff];
      wgt = (raw < 0) ? rr.y : rr.x;
    }
    tokI[tid] = raw; tokW[tid] = wgt;
  }
  __syncthreads();

  if (xbf != nullptr) {                   // stage Xtile from bf16 (no convert)
#pragma unroll
    for (int it = 0; it < 4; ++it) {
      int G = tid + 512*it;
      int row = G >> 5, g = G & 31;
      int tok = tokI[row] & 0x7fffffff;
      u16x8 v = *(const u16x8*)(xbf + (size_t)tok*256 + g*8);
      *(u16x8*)(lds0 + row*512 + ((g ^ (row & 7)) << 4)) = v;
    }
  } else {                                // fallback: fp32 gather + convert
#pragma unroll
    for (int it = 0; it < 4; ++it) {
      int G = tid + 512*it;
      int row = G >> 5, g = G & 31;
      int tok = tokI[row] & 0x7fffffff;
      const float* src = x + (size_t)tok*256 + g*8;
      f32x4 va = *(const f32x4*)src;
      f32x4 vb = *(const f32x4*)(src + 4);
      u16x8 pk;
      pk[0]=f2bf(va.x); pk[1]=f2bf(va.y); pk[2]=f2bf(va.z); pk[3]=f2bf(va.w);
      pk[4]=f2bf(vb.x); pk[5]=f2bf(vb.y); pk[6]=f2bf(vb.z); pk[7]=f2bf(vb.w);
      *(u16x8*)(lds0 + row*512 + ((g ^ (row & 7)) << 4)) = pk;
    }
  }
  __syncthreads();

  const int rowA = wm*32 + l31;
  const int swA = rowA & 7;

  // ---- L1: [64x256] = X @ W1; wave covers 64 cols (wn), 2 acc ----------------
  const u16* w1e = w1f + (size_t)e*65536 + (size_t)(wn*2)*8192 + l*8;
  f32x16 acc[2];
  acc[0] = (f32x16)0.f; acc[1] = (f32x16)0.f;
#pragma unroll 4
  for (int ks = 0; ks < 16; ++ks) {
    int gk = ks*2 + lh;
    bf16x8 af = *(const bf16x8*)(lds0 + rowA*512 + ((gk ^ swA) << 4));
#pragma unroll
    for (int a = 0; a < 2; ++a) {
      bf16x8 bf = *(const bf16x8*)(w1e + a*8192 + ks*512);
      acc[a] = __builtin_amdgcn_mfma_f32_32x32x16_bf16(af, bf, acc[a], 0, 0, 0);
    }
  }

  int colA[2]; float cb[2];
#pragma unroll
  for (int a = 0; a < 2; ++a) {
    colA[a] = wn*64 + a*32 + l31;
    cb[a] = eb1[e*256 + colA[a]];
  }
#pragma unroll
  for (int a = 0; a < 2; ++a)
#pragma unroll
    for (int j = 0; j < 16; ++j) acc[a][j] += cb[a];

#pragma unroll
  for (int j = 0; j < 16; ++j) {          // LN1 partials over wave's 64 cols
    float s = acc[0][j] + acc[1][j];
    float q = acc[0][j]*acc[0][j] + acc[1][j]*acc[1][j];
#pragma unroll
    for (int m = 1; m <= 16; m <<= 1) { s += __shfl_xor(s, m); q += __shfl_xor(q, m); }
    if (l31 == 0) {
      int row = wm*32 + (j&3) + 8*(j>>2) + 4*lh;
      partS[row*4 + wn] = s;
      partQ[row*4 + wn] = q;
    }
  }
  __syncthreads();
  if (tid < 64) {
    float s = partS[tid*4]+partS[tid*4+1]+partS[tid*4+2]+partS[tid*4+3];
    float q = partQ[tid*4]+partQ[tid*4+1]+partQ[tid*4+2]+partQ[tid*4+3];
    float m = s * (1.f/256.f);
    float var = q * (1.f/256.f) - m*m;
    meanv[tid] = m; rsv[tid] = rsqrtf(var + 1e-5f);
  }
  __syncthreads();

  float ga[2], bb[2];
#pragma unroll
  for (int a = 0; a < 2; ++a) { ga[a]=g1v[e*256+colA[a]]; bb[a]=b1v[e*256+colA[a]]; }
#pragma unroll
  for (int a = 0; a < 2; ++a) {           // H1 -> lds0 (overwrites X)
#pragma unroll
    for (int j = 0; j < 16; ++j) {
      int row = wm*32 + (j&3) + 8*(j>>2) + 4*lh;
      float v = (acc[a][j] - meanv[row]) * rsv[row] * ga[a] + bb[a];
      v = gelu_fast(v);
      float o = __shfl_xor(v, 1);
      if ((l & 1) == 0) {
        unsigned pk2 = (unsigned)f2bf(v) | ((unsigned)f2bf(o) << 16);
        int cbyte = colA[a]*2;
        *(unsigned*)(lds0 + row*512 + (cbyte ^ ((row & 7) << 4))) = pk2;
      }
    }
  }
  __syncthreads();

  // ---- L2: [64x128] = H1 @ W2; wave covers 32 cols (wn), 1 acc ---------------
  const u16* w2e = w2f + (size_t)e*32768 + (size_t)wn*8192 + l*8;
  f32x16 accB = (f32x16)0.f;
#pragma unroll 4
  for (int ks = 0; ks < 16; ++ks) {
    int gk = ks*2 + lh;
    bf16x8 af = *(const bf16x8*)(lds0 + rowA*512 + ((gk ^ swA) << 4));
    bf16x8 bf = *(const bf16x8*)(w2e + ks*512);
    accB = __builtin_amdgcn_mfma_f32_32x32x16_bf16(af, bf, accB, 0, 0, 0);
  }
  int colB = wn*32 + l31;
  float cb2 = eb2[e*128 + colB];
#pragma unroll
  for (int j = 0; j < 16; ++j) accB[j] += cb2;

#pragma unroll
  for (int j = 0; j < 16; ++j) {          // LN2 partials over wave's 32 cols
    float s = accB[j];
    float q = accB[j]*accB[j];
#pragma unroll
    for (int m = 1; m <= 16; m <<= 1) { s += __shfl_xor(s, m); q += __shfl_xor(q, m); }
    if (l31 == 0) {
      int row = wm*32 + (j&3) + 8*(j>>2) + 4*lh;
      partS[row*4 + wn] = s;
      partQ[row*4 + wn] = q;
    }
  }
  __syncthreads();
  if (tid < 64) {
    float s = partS[tid*4]+partS[tid*4+1]+partS[tid*4+2]+partS[tid*4+3];
    float q = partQ[tid*4]+partQ[tid*4+1]+partQ[tid*4+2]+partQ[tid*4+3];
    float m = s * (1.f/128.f);
    float var = q * (1.f/128.f) - m*m;
    meanv[tid] = m; rsv[tid] = rsqrtf(var + 1e-5f);
  }
  __syncthreads();
  {
    float ga2 = g2v[e*128 + colB], bb2 = b2v[e*128 + colB];
#pragma unroll
    for (int j = 0; j < 16; ++j) {        // H2 -> lds0 [64][16][16B]
      int row = wm*32 + (j&3) + 8*(j>>2) + 4*lh;
      float v = (accB[j] - meanv[row]) * rsv[row] * ga2 + bb2;
      v = gelu_fast(v);
      float o = __shfl_xor(v, 1);
      if ((l & 1) == 0) {
        unsigned pk2 = (unsigned)f2bf(v) | ((unsigned)f2bf(o) << 16);
        int cbyte = colB*2;
        *(unsigned*)(lds0 + row*256 + (cbyte ^ ((row & 7) << 4))) = pk2;
      }
    }
  }
  __syncthreads();

  if (w < 2) {                            // ---- L3: eo = H2 @ W3 (+b3) -------
    const u16* w3e = w3f + (size_t)e*4096 + l*8;
    f32x16 accC = (f32x16)0.f;
    int rowC = w*32 + l31; int swC = rowC & 7;
#pragma unroll
    for (int ks = 0; ks < 8; ++ks) {
      int gk = ks*2 + lh;
      bf16x8 af = *(const bf16x8*)(lds0 + rowC*256 + ((gk ^ swC) << 4));
      bf16x8 bf = *(const bf16x8*)(w3e + ks*512);
      accC = __builtin_amdgcn_mfma_f32_32x32x16_bf16(af, bf, accC, 0, 0, 0);
    }
    float b3 = (l31 < 10) ? eb3[e*10 + l31] : 0.f;
#pragma unroll
    for (int j = 0; j < 16; ++j) {
      int rl = w*32 + (j&3) + 8*(j>>2) + 4*lh;
      if (rl < nvalid && l31 < 10) {
        int raw = tokI[rl];
        int tok = raw & 0x7fffffff;
        float val = (accC[j] + b3) * tokW[rl];
        if (ob0) {
          float* dst = (raw < 0) ? ob1 : ob0;
          dst[(size_t)tok*10 + l31] = val;
        } else {
          atomicAdd(outp + (size_t)tok*10 + l31, val);
        }
      }
    }
  }
}

__global__ __launch_bounds__(256) void combine_kernel(
    const float* __restrict__ b0, const float* __restrict__ b1,
    float* __restrict__ y, int n)
{
  int i = blockIdx.x * 256 + threadIdx.x;
  if (i < n) y[i] = b0[i] + b1[i];
}

extern "C" void kernel_launch(void* const* d_in, const int* in_sizes, int n_in,
                              void* d_out, int out_size, void* d_ws, size_t ws_size,
                              hipStream_t stream) {
  const float* x     = (const float*)d_in[0];
  const float* gW1   = (const float*)d_in[1];
  const float* gb1   = (const float*)d_in[2];
  const float* glng  = (const float*)d_in[3];
  const float* glnb  = (const float*)d_in[4];
  const float* gW2   = (const float*)d_in[5];
  const float* gb2   = (const float*)d_in[6];
  const float* temp  = (const float*)d_in[7];
  const float* eW1   = (const float*)d_in[8];
  const float* eb1   = (const float*)d_in[9];
  const float* elng1 = (const float*)d_in[10];
  const float* elnb1 = (const float*)d_in[11];
  const float* eW2   = (const float*)d_in[12];
  const float* eb2   = (const float*)d_in[13];
  const float* elng2 = (const float*)d_in[14];
  const float* elnb2 = (const float*)d_in[15];
  const float* eW3   = (const float*)d_in[16];
  const float* eb3   = (const float*)d_in[17];

  char* ws = (char*)d_ws;
  int*    cnt     = (int*)(ws + O_CNT);
  int*    refCnt  = (int*)(ws + O_CNT + 32);
  int*    list    = (int*)(ws + O_LIST);
  int*    rcode   = (int*)(ws + O_RCODE);
  float2* rgp     = (float2*)(ws + O_RG);
  int*    refList = (int*)(ws + O_RL);
  u16*    w1f     = (u16*)(ws + O_W1);
  u16*    w2f     = (u16*)(ws + O_W2);
  u16*    w3f     = (u16*)(ws + O_W3);
  u16*    w1g     = (u16*)(ws + O_W1G);
  bool useBuf     = ws_size >= O_XBF;
  float*  b0      = useBuf ? (float*)(ws + O_B0) : nullptr;
  float*  b1      = useBuf ? (float*)(ws + O_B1) : nullptr;
  u16*    xbf     = (ws_size >= O_XBF + (size_t)N_TOK*512)
                    ? (u16*)(ws + O_XBF) : nullptr;

  hipMemsetAsync(cnt, 0, 256, stream);
  if (!useBuf) hipMemsetAsync(d_out, 0, (size_t)out_size * 4, stream);

  prep_kernel<<<432, 256, 0, stream>>>(eW1, eW2, eW3, gW1, w1f, w2f, w3f, w1g);

  int gate_smem = 151552;
  hipFuncSetAttribute((const void*)gate_kernel,
                      hipFuncAttributeMaxDynamicSharedMemorySize, gate_smem);
  gate_kernel<<<512, 512, gate_smem, stream>>>(x, w1g, gb1, glng, glnb, gW2, gb2,
                                               temp, rcode, rgp, refCnt, refList, xbf);

  refine_kernel<<<128, 256, 0, stream>>>(x, gW1, gb1, glng, glnb, gW2, gb2, temp,
                                         refCnt, refList, rcode, rgp);

  lists_kernel<<<512, 256, 0, stream>>>(rcode, cnt, list);

  int exp_smem = 35840;
  hipFuncSetAttribute((const void*)expert_kernel,
                      hipFuncAttributeMaxDynamicSharedMemorySize, exp_smem);
  expert_kernel<<<dim3(2048, 8), 512, exp_smem, stream>>>(
      x, xbf, w1f, w2f, w3f, cnt, list, rgp,
      eb1, elng1, elnb1, eb2, elng2, elnb2, eb3, b0, b1, (float*)d_out);

  if (useBuf)
    combine_kernel<<<(N_TOK*NOUT + 255)/256, 256, 0, stream>>>(
        b0, b1, (float*)d_out, N_TOK*NOUT);
}